// Round 4
// baseline (452.434 us; speedup 1.0000x reference)
//
#include <hip/hip_runtime.h>
#include <math.h>

#define Bsz  4
#define Tlen 4096
#define Cdim 512
#define CUT  (-12.0f)   // tail std ~6e-4 << absmax budget
#define NBE  8388608    // Bsz*Tlen*Cdim

typedef unsigned int u32;
typedef _Float16 f16;
typedef __attribute__((ext_vector_type(8))) _Float16 f16x8;
typedef __attribute__((ext_vector_type(4))) float floatx4;
#define MFMA_F16(a,b,c) __builtin_amdgcn_mfma_f32_16x16x32_f16((a),(b),(c),0,0,0)

union pun8 { uint4 u; f16x8 f; };

__device__ __forceinline__ u32 pack2(f16 a, f16 b) {
    return (u32)__builtin_bit_cast(unsigned short, a) |
           ((u32)__builtin_bit_cast(unsigned short, b) << 16);
}
__device__ __forceinline__ u32 splitpack(float v) {
    f16 h = (f16)v;
    f16 l = (f16)(v - (float)h);
    return pack2(h, l);
}
// 8 packed (h|l) u32 -> hi f16x8 + lo f16x8 (v_perm_b32, 8 ops)
__device__ __forceinline__ void unpack8(const u32* p, f16x8& h, f16x8& l) {
    uint4 q0 = *(const uint4*)p;
    uint4 q1 = *(const uint4*)(p + 4);
    pun8 ph, pl;
    ph.u.x = __builtin_amdgcn_perm(q0.y, q0.x, 0x05040100u);
    pl.u.x = __builtin_amdgcn_perm(q0.y, q0.x, 0x07060302u);
    ph.u.y = __builtin_amdgcn_perm(q0.w, q0.z, 0x05040100u);
    pl.u.y = __builtin_amdgcn_perm(q0.w, q0.z, 0x07060302u);
    ph.u.z = __builtin_amdgcn_perm(q1.y, q1.x, 0x05040100u);
    pl.u.z = __builtin_amdgcn_perm(q1.y, q1.x, 0x07060302u);
    ph.u.w = __builtin_amdgcn_perm(q1.w, q1.z, 0x05040100u);
    pl.u.w = __builtin_amdgcn_perm(q1.w, q1.z, 0x07060302u);
    h = ph.f; l = pl.f;
}

// ---------------------------------------------------------------------------
// Kernel A (fused prep): blocks 0..4095 = X split->packed u32; 4096..4287 =
// W transpose -> WT f16; 4288 = gamma prefix scan + decay tables + worklist.
// ---------------------------------------------------------------------------
__global__ __launch_bounds__(256) void prep_kernel(
    const float* __restrict__ X,
    const float* __restrict__ WQ, const float* __restrict__ WK,
    const float* __restrict__ WV,
    u32* __restrict__ Xc, f16* __restrict__ WT,
    float* __restrict__ Lg, float* __restrict__ Wfin,
    int* __restrict__ sLo, int* __restrict__ Wp) {
    __shared__ char pshm[18432];
    int bid = blockIdx.x, tid = threadIdx.x;
    if (bid < 4096) {
        size_t i = ((size_t)bid * 256 + tid) * 8;
        float4 a = *(const float4*)(X + i);
        float4 b = *(const float4*)(X + i + 4);
        uint4 o0, o1;
        o0.x = splitpack(a.x); o0.y = splitpack(a.y);
        o0.z = splitpack(a.z); o0.w = splitpack(a.w);
        o1.x = splitpack(b.x); o1.y = splitpack(b.y);
        o1.z = splitpack(b.z); o1.w = splitpack(b.w);
        *(uint4*)(Xc + i) = o0;
        *(uint4*)(Xc + i + 4) = o1;
    } else if (bid < 4288) {
        f16* tile = (f16*)pshm;   // [64][72]
        int wb = bid - 4096;
        int mat = wb >> 6, rem = wb & 63;
        int k0 = (rem >> 3) * 64, n0 = (rem & 7) * 64;
        const float* W = (mat == 0) ? WQ : (mat == 1) ? WK : WV;
        int row = tid >> 2, q = tid & 3;
        const float* src = W + (size_t)(k0 + row) * Cdim + n0 + q * 16;
        float vv[16];
#pragma unroll
        for (int j = 0; j < 4; ++j) {
            float4 v = *(const float4*)(src + j * 4);
            vv[j*4+0]=v.x; vv[j*4+1]=v.y; vv[j*4+2]=v.z; vv[j*4+3]=v.w;
        }
#pragma unroll
        for (int j = 0; j < 16; ++j) tile[(q * 16 + j) * 72 + row] = (f16)vv[j];
        __syncthreads();
        f16x8 r0 = *(const f16x8*)(tile + row * 72 + q * 16);
        f16x8 r1 = *(const f16x8*)(tile + row * 72 + q * 16 + 8);
        f16* dst = WT + ((size_t)mat * Cdim + n0 + row) * Cdim + k0 + q * 16;
        *(f16x8*)dst = r0;
        *(f16x8*)(dst + 8) = r1;
    } else {
        float* Lsh = (float*)pshm;                 // 4097
        float* sums = (float*)(pshm + 16400);      // 256
        int* cnts = (int*)(pshm + 17424);          // 64
        float lg[16];
        float local = 0.f;
        int base = tid * 16;
#pragma unroll
        for (int i = 0; i < 16; ++i) {
            int t = base + i;
            float g = 0.96f + 0.03f * ((float)t * (1.0f / 4095.0f));
            lg[i] = logf(g);
            local += lg[i];
        }
        sums[tid] = local;
        __syncthreads();
        for (int off = 1; off < 256; off <<= 1) {
            float v = sums[tid];
            if (tid >= off) v += sums[tid - off];
            __syncthreads();
            sums[tid] = v;
            __syncthreads();
        }
        float pre = (tid == 0) ? 0.f : sums[tid - 1];
#pragma unroll
        for (int i = 0; i < 16; ++i) {
            Lsh[base + i] = pre;
            pre += lg[i];
        }
        if (tid == 255) Lsh[4096] = pre;
        __syncthreads();
        for (int t = tid; t < 4097; t += 256) Lg[t] = Lsh[t];
        float LT = Lsh[4096];
        for (int s = tid; s < 4096; s += 256) Wfin[s] = __expf(LT - Lsh[s + 1]);
        if (tid < 64) {
            float ref = Lsh[tid * 64 + 1];
            int st_hi = tid >> 1;
            int lo = st_hi;
            for (int st = 0; st < st_hi; ++st)
                if (ref - Lsh[st * 128 + 128] > CUT) { lo = st; break; }
            sLo[tid] = lo;
            cnts[tid] = st_hi - lo + 1;
        }
        __syncthreads();
        if (tid == 0) {
            int acc = 0;
            for (int i = 0; i < 64; ++i) { Wp[i] = acc; acc += cnts[i]; }
            Wp[64] = acc;
        }
    }
}

// ---------------------------------------------------------------------------
// Kernel B: QKV projection, barrier-free direct-fragment MFMA main loop.
// A-frags direct from Xc (packed h|l u32), B-frags direct from WT (f16).
// Epilogue: Q -> packed u32 row-major (LDS bounce); K -> KT direct + Kf
// row-major (bounce); V -> VT direct.
// ---------------------------------------------------------------------------
__global__ __launch_bounds__(256, 2) void qkv_mfma(
    const u32* __restrict__ Xc, const f16* __restrict__ WT,
    const float* __restrict__ bQ, const float* __restrict__ bK,
    const float* __restrict__ bV,
    u32* __restrict__ Qc, f16* __restrict__ Kf,
    f16* __restrict__ KT, f16* __restrict__ VT) {
    __shared__ char smem[67584];   // u32[128][132] / f16[128][136] views
    int tid = threadIdx.x, lane = tid & 63, wid = tid >> 6;
    int l16 = lane & 15, quad = lane >> 4;
    int mw = wid & 1, nw = wid >> 1;
    int xb = blockIdx.x;             // 0..11 (mat*4 + n-tile)
    int mat = xb >> 2, n0l = (xb & 3) * 128;
    int m0 = blockIdx.y * 128;

    floatx4 acc[4][4];
#pragma unroll
    for (int i = 0; i < 4; ++i)
#pragma unroll
        for (int j = 0; j < 4; ++j) acc[i][j] = (floatx4)0.f;

    const u32* abase = Xc + (size_t)(m0 + mw * 64 + l16) * Cdim;
    const f16* bbase = WT + ((size_t)(mat * Cdim) + n0l + nw * 64 + l16) * Cdim;

#pragma unroll 2
    for (int kcf = 0; kcf < 16; ++kcf) {
        int ko = kcf * 32 + quad * 8;
        f16x8 ah[4], al[4], bw[4];
#pragma unroll
        for (int mt = 0; mt < 4; ++mt)
            unpack8(abase + (size_t)mt * 16 * Cdim + ko, ah[mt], al[mt]);
#pragma unroll
        for (int nt = 0; nt < 4; ++nt)
            bw[nt] = *(const f16x8*)(bbase + (size_t)nt * 16 * Cdim + ko);
#pragma unroll
        for (int mt = 0; mt < 4; ++mt)
#pragma unroll
            for (int nt = 0; nt < 4; ++nt) {
                acc[mt][nt] = MFMA_F16(ah[mt], bw[nt], acc[mt][nt]);
                acc[mt][nt] = MFMA_F16(al[mt], bw[nt], acc[mt][nt]);
            }
    }

    const float* bias = (mat == 0) ? bQ : (mat == 1) ? bK : bV;
    float bv[4];
#pragma unroll
    for (int nt = 0; nt < 4; ++nt) bv[nt] = bias[n0l + nw * 64 + nt * 16 + l16];
    float cv[4][4][4];
#pragma unroll
    for (int mt = 0; mt < 4; ++mt)
#pragma unroll
        for (int nt = 0; nt < 4; ++nt)
#pragma unroll
            for (int r = 0; r < 4; ++r) cv[mt][nt][r] = acc[mt][nt][r] + bv[nt];

    int b = m0 >> 12, tloc = m0 & 4095;

    if (mat == 2) {
#pragma unroll
        for (int mt = 0; mt < 4; ++mt)
#pragma unroll
            for (int nt = 0; nt < 4; ++nt) {
                int d = n0l + nw * 64 + nt * 16 + l16;
                int t = tloc + mw * 64 + mt * 16 + quad * 4;
                uint2 w;
                w.x = pack2((f16)cv[mt][nt][0], (f16)cv[mt][nt][1]);
                w.y = pack2((f16)cv[mt][nt][2], (f16)cv[mt][nt][3]);
                *(uint2*)(VT + ((size_t)(b * Cdim + d)) * Tlen + t) = w;
            }
    } else if (mat == 1) {
#pragma unroll
        for (int mt = 0; mt < 4; ++mt)
#pragma unroll
            for (int nt = 0; nt < 4; ++nt) {
                int d = n0l + nw * 64 + nt * 16 + l16;
                int t = tloc + mw * 64 + mt * 16 + quad * 4;
                uint2 w;
                w.x = pack2((f16)cv[mt][nt][0], (f16)cv[mt][nt][1]);
                w.y = pack2((f16)cv[mt][nt][2], (f16)cv[mt][nt][3]);
                *(uint2*)(KT + ((size_t)(b * Cdim + d)) * Tlen + t) = w;
            }
        f16* sKf = (f16*)smem;   // [128][136]
#pragma unroll
        for (int mt = 0; mt < 4; ++mt)
#pragma unroll
            for (int nt = 0; nt < 4; ++nt)
#pragma unroll
                for (int r = 0; r < 4; ++r)
                    sKf[(mw * 64 + mt * 16 + quad * 4 + r) * 136 +
                        nw * 64 + nt * 16 + l16] = (f16)cv[mt][nt][r];
        __syncthreads();
        {
            int r2 = tid >> 1, h2 = tid & 1;
            f16* dst = Kf + (size_t)(m0 + r2) * Cdim + n0l + h2 * 64;
#pragma unroll
            for (int j = 0; j < 8; ++j)
                *(uint4*)(dst + j * 8) = *(const uint4*)(sKf + r2 * 136 + h2 * 64 + j * 8);
        }
    } else {
        u32* sQ = (u32*)smem;    // [128][132]
#pragma unroll
        for (int mt = 0; mt < 4; ++mt)
#pragma unroll
            for (int nt = 0; nt < 4; ++nt)
#pragma unroll
                for (int r = 0; r < 4; ++r)
                    sQ[(mw * 64 + mt * 16 + quad * 4 + r) * 132 +
                       nw * 64 + nt * 16 + l16] = splitpack(cv[mt][nt][r]);
        __syncthreads();
        {
            int r2 = tid >> 1, h2 = tid & 1;
            u32* dst = Qc + (size_t)(m0 + r2) * Cdim + n0l + h2 * 64;
#pragma unroll
            for (int j = 0; j < 16; ++j)
                *(uint4*)(dst + j * 4) = *(const uint4*)(sQ + r2 * 132 + h2 * 64 + j * 4);
        }
    }
}

// ---------------------------------------------------------------------------
// Kernel C: attention. 256 blocks x 512 thr (8 waves). t-tile 64, s-tile 128,
// worklist-balanced. Phase1/2 fragments loaded DIRECTLY from global (L2) —
// no staging LDS, no barriers in GEMM loops. Only P transits LDS (packed
// h|l u32, XOR-swizzled: conflict-free reads, 2-way-free writes).
// 2 barriers per work item total.
// ---------------------------------------------------------------------------
__global__ __launch_bounds__(512, 2) void attn_mfma(
    const u32* __restrict__ Qc, const f16* __restrict__ Kf,
    const f16* __restrict__ VT, const float* __restrict__ Lg,
    const int* __restrict__ sLo, const int* __restrict__ Wp,
    float* __restrict__ Oacc) {
    __shared__ u32 sPc[64 * 132];   // 33792 B

    int tid = threadIdx.x, lane = tid & 63, wid = tid >> 6;
    int l16 = lane & 15, quad = lane >> 4;
    int mw = wid & 1, nw = wid >> 1;     // phase1: t-half / s-quarter

    int b = blockIdx.x >> 6, wb = blockIdx.x & 63;
    int Wtot = Wp[64];
    int i0 = (wb * Wtot) >> 6;
    int i1 = ((wb + 1) * Wtot) >> 6;
    size_t bT = (size_t)b * Tlen;

    int cur = i0, tt = 0;
    while (cur < i1) {
        while (Wp[tt + 1] <= cur) ++tt;
        int t0 = tt * 64;
        int jEnd = min(Wp[tt + 1], i1) - Wp[tt];
        int j = cur - Wp[tt];
        int lo = sLo[tt];
        cur = Wp[tt] + jEnd;

        float aT[2][4];
#pragma unroll
        for (int t2 = 0; t2 < 2; ++t2)
#pragma unroll
            for (int r = 0; r < 4; ++r)
                aT[t2][r] = Lg[t0 + mw * 32 + t2 * 16 + quad * 4 + r + 1];

        floatx4 oacc[4][4];
#pragma unroll
        for (int i = 0; i < 4; ++i)
#pragma unroll
            for (int jj = 0; jj < 4; ++jj) oacc[i][jj] = (floatx4)0.f;

        for (; j < jEnd; ++j) {
            int s0 = (lo + j) * 128;
            float lsp[2];
#pragma unroll
            for (int st = 0; st < 2; ++st)
                lsp[st] = Lg[s0 + nw * 32 + st * 16 + l16 + 1];

            floatx4 pacc[2][2];
#pragma unroll
            for (int i = 0; i < 2; ++i)
#pragma unroll
                for (int jj = 0; jj < 2; ++jj) pacc[i][jj] = (floatx4)0.f;

            // ---- phase 1: P = (Qh+Ql) . K^T, direct-frag, no LDS
            const u32* qbase = Qc + (bT + t0 + mw * 32 + l16) * Cdim;
            const f16* kbase = Kf + (bT + s0 + nw * 32 + l16) * Cdim;
#pragma unroll 2
            for (int kcf = 0; kcf < 16; ++kcf) {
                int ko = kcf * 32 + quad * 8;
                f16x8 ah0, al0, ah1, al1;
                unpack8(qbase + ko, ah0, al0);
                unpack8(qbase + 16 * Cdim + ko, ah1, al1);
#pragma unroll
                for (int st = 0; st < 2; ++st) {
                    f16x8 bk = *(const f16x8*)(kbase + (size_t)st * 16 * Cdim + ko);
                    pacc[0][st] = MFMA_F16(ah0, bk, pacc[0][st]);
                    pacc[0][st] = MFMA_F16(al0, bk, pacc[0][st]);
                    pacc[1][st] = MFMA_F16(ah1, bk, pacc[1][st]);
                    pacc[1][st] = MFMA_F16(al1, bk, pacc[1][st]);
                }
            }

            // ---- weight + mask + pack into swizzled LDS
            __syncthreads();   // prior phase2 reads of sPc complete
#pragma unroll
            for (int t2 = 0; t2 < 2; ++t2)
#pragma unroll
                for (int st = 0; st < 2; ++st)
#pragma unroll
                    for (int r = 0; r < 4; ++r) {
                        int tl = mw * 32 + t2 * 16 + quad * 4 + r;
                        int sl = nw * 32 + st * 16 + l16;
                        int t = t0 + tl, s = s0 + sl;
                        float p = pacc[t2][st][r];
                        p = (s <= t) ? p * __expf(aT[t2][r] - lsp[st]) : 0.f;
                        sPc[tl * 132 + (sl ^ ((tl & 7) << 4))] = splitpack(p);
                    }
            __syncthreads();

            // ---- phase 2: Oacc += (Ph+Pl) . V, V frags direct from global
            const f16* vbase = VT + ((size_t)(b * Cdim + wid * 64 + l16)) * Tlen + s0;
#pragma unroll
            for (int kf = 0; kf < 4; ++kf) {
                int sb = kf * 32 + quad * 8;
                f16x8 ph[4], pl[4];
#pragma unroll
                for (int mt = 0; mt < 4; ++mt) {
                    int tl = mt * 16 + l16;
                    unpack8(&sPc[tl * 132 + (sb ^ ((tl & 7) << 4))], ph[mt], pl[mt]);
                }
#pragma unroll
                for (int nt = 0; nt < 4; ++nt) {
                    f16x8 vb = *(const f16x8*)(vbase + (size_t)nt * 16 * Tlen + sb);
#pragma unroll
                    for (int mt = 0; mt < 4; ++mt) {
                        oacc[mt][nt] = MFMA_F16(ph[mt], vb, oacc[mt][nt]);
                        oacc[mt][nt] = MFMA_F16(pl[mt], vb, oacc[mt][nt]);
                    }
                }
            }
        }

        // ---- flush partials (atomic; Oacc pre-zeroed)
#pragma unroll
        for (int mt = 0; mt < 4; ++mt)
#pragma unroll
            for (int nt = 0; nt < 4; ++nt)
#pragma unroll
                for (int r = 0; r < 4; ++r) {
                    int t = t0 + mt * 16 + quad * 4 + r;
                    int d = wid * 64 + nt * 16 + l16;
                    atomicAdd(Oacc + (bT + t) * Cdim + d, oacc[mt][nt][r]);
                }
    }
}

// ---------------------------------------------------------------------------
// Kernel D: tanh epilogue
// ---------------------------------------------------------------------------
__global__ __launch_bounds__(256) void tanh_kernel(const float* __restrict__ Oa,
                                                   float* __restrict__ out) {
    size_t i = (size_t)blockIdx.x * 256 + threadIdx.x;
    size_t n4 = (size_t)NBE / 4;
    for (; i < n4; i += (size_t)gridDim.x * 256) {
        float4 v = ((const float4*)Oa)[i];
        float4 o;
        o.x = tanhf(v.x); o.y = tanhf(v.y); o.z = tanhf(v.z); o.w = tanhf(v.w);
        ((float4*)out)[i] = o;
    }
}

// ---------------------------------------------------------------------------
// Kernel E: S_final = sum_s Wfin[s] * K[s]^T V[s] via f16 MFMA on KT/VT.
// ---------------------------------------------------------------------------
__global__ __launch_bounds__(256) void sfinal_mfma(
    const f16* __restrict__ KT, const f16* __restrict__ VT,
    const float* __restrict__ Lg, const float* __restrict__ Wfin,
    float* __restrict__ S) {
    __shared__ f16 sA[64 * 72];
    __shared__ f16 sB2[64 * 72];
    int tid = threadIdx.x, lane = tid & 63, wid = tid >> 6;
    int l16 = lane & 15, quad = lane >> 4;
    int wv_c = wid & 1, wv_d = wid >> 1;
    int c0 = blockIdx.x * 64, d0 = blockIdx.y * 64, b = blockIdx.z;
    float LT = Lg[Tlen];
    floatx4 acc[2][2];
#pragma unroll
    for (int i = 0; i < 2; ++i)
#pragma unroll
        for (int jj = 0; jj < 2; ++jj) acc[i][jj] = (floatx4)0.f;

    int s0start = Tlen - 64;
    for (int s0 = 0; s0 < Tlen; s0 += 64)
        if (LT - Lg[s0 + 64] > CUT) { s0start = s0; break; }

    int row = tid >> 2, q = tid & 3;
    for (int s0 = s0start; s0 < Tlen; s0 += 64) {
        __syncthreads();
        {
            const f16* g = KT + ((size_t)(b * Cdim + c0 + row)) * Tlen + s0 + q * 16;
            f16x8 u0 = *(const f16x8*)g;
            f16x8 u1 = *(const f16x8*)(g + 8);
            float wv[16];
#pragma unroll
            for (int jj = 0; jj < 4; ++jj) {
                float4 w4 = *(const float4*)(Wfin + s0 + q * 16 + jj * 4);
                wv[jj*4+0]=w4.x; wv[jj*4+1]=w4.y; wv[jj*4+2]=w4.z; wv[jj*4+3]=w4.w;
            }
            f16x8 o0, o1;
#pragma unroll
            for (int jj = 0; jj < 8; ++jj) o0[jj] = (f16)((float)u0[jj] * wv[jj]);
#pragma unroll
            for (int jj = 0; jj < 8; ++jj) o1[jj] = (f16)((float)u1[jj] * wv[8 + jj]);
            *(f16x8*)(sA + row * 72 + q * 16) = o0;
            *(f16x8*)(sA + row * 72 + q * 16 + 8) = o1;
            const f16* gv = VT + ((size_t)(b * Cdim + d0 + row)) * Tlen + s0 + q * 16;
            uint4 v0 = *(const uint4*)gv, v1 = *(const uint4*)(gv + 8);
            *(uint4*)(sB2 + row * 72 + q * 16) = v0;
            *(uint4*)(sB2 + row * 72 + q * 16 + 8) = v1;
        }
        __syncthreads();
#pragma unroll
        for (int ks = 0; ks < 2; ++ks) {
            int ko = ks * 32 + quad * 8;
            f16x8 a0 = *(const f16x8*)(sA + (wv_c * 32 + l16) * 72 + ko);
            f16x8 a1 = *(const f16x8*)(sA + (wv_c * 32 + 16 + l16) * 72 + ko);
            f16x8 b0 = *(const f16x8*)(sB2 + (wv_d * 32 + l16) * 72 + ko);
            f16x8 b1 = *(const f16x8*)(sB2 + (wv_d * 32 + 16 + l16) * 72 + ko);
            acc[0][0] = MFMA_F16(a0, b0, acc[0][0]);
            acc[0][1] = MFMA_F16(a0, b1, acc[0][1]);
            acc[1][0] = MFMA_F16(a1, b0, acc[1][0]);
            acc[1][1] = MFMA_F16(a1, b1, acc[1][1]);
        }
    }
#pragma unroll
    for (int ct = 0; ct < 2; ++ct)
#pragma unroll
        for (int dt = 0; dt < 2; ++dt)
#pragma unroll
            for (int r = 0; r < 4; ++r) {
                int c = c0 + wv_c * 32 + ct * 16 + quad * 4 + r;
                int d = d0 + wv_d * 32 + dt * 16 + l16;
                S[((size_t)(b * Cdim + c)) * Cdim + d] = acc[ct][dt][r];
            }
}

// ---------------------------------------------------------------------------
extern "C" void kernel_launch(void* const* d_in, const int* in_sizes, int n_in,
                              void* d_out, int out_size, void* d_ws, size_t ws_size,
                              hipStream_t stream) {
    (void)in_sizes; (void)n_in; (void)out_size; (void)ws_size;
    const float* X  = (const float*)d_in[0];
    const float* WQ = (const float*)d_in[2];
    const float* bQ = (const float*)d_in[3];
    const float* WK = (const float*)d_in[4];
    const float* bK = (const float*)d_in[5];
    const float* WV = (const float*)d_in[6];
    const float* bV = (const float*)d_in[7];

    float* out   = (float*)d_out;
    float* S_out = out + (size_t)NBE;

    char* ws = (char*)d_ws;
    u32*   Xc   = (u32*)(ws);                         // 4*NBE B (== Oacc later)
    float* Oacc = (float*)(ws);
    u32*   Qc   = (u32*)(ws + 4ull * NBE);            // 4*NBE
    f16*   Kf   = (f16*)(ws + 8ull * NBE);            // 2*NBE
    f16*   KT   = (f16*)(ws + 10ull * NBE);           // 2*NBE
    f16*   VT   = (f16*)(ws + 12ull * NBE);           // 2*NBE
    f16*   WT   = (f16*)(ws + 14ull * NBE);           // 1.57 MB
    char*  tail = ws + 14ull * NBE + (2u << 20);
    float* Lg   = (float*)(tail);                     // 4097
    float* Wfin = (float*)(tail + 16512);             // 4096
    int*   sLo  = (int*)(tail + 16512 + 16384);
    int*   Wp   = (int*)(tail + 16512 + 16384 + 256);

    prep_kernel<<<4289, 256, 0, stream>>>(X, WQ, WK, WV, Xc, WT, Lg, Wfin, sLo, Wp);
    qkv_mfma<<<dim3(12, 128), 256, 0, stream>>>(Xc, WT, bQ, bK, bV, Qc, Kf, KT, VT);
    hipMemsetAsync(Oacc, 0, (size_t)NBE * 4, stream);   // Oacc aliases Xc (dead)
    attn_mfma<<<256, 512, 0, stream>>>(Qc, Kf, VT, Lg, sLo, Wp, Oacc);
    tanh_kernel<<<2048, 256, 0, stream>>>(Oacc, out);
    sfinal_mfma<<<dim3(8, 8, Bsz), 256, 0, stream>>>(KT, VT, Lg, Wfin, S_out);
}

// Round 5
// 301.436 us; speedup vs baseline: 1.5009x; 1.5009x over previous
//
#include <hip/hip_runtime.h>
#include <math.h>

#define Bsz  4
#define Tlen 4096
#define Cdim 512
#define CUT  (-12.0f)   // neglected-tail std ~6e-4 << absmax budget
#define NBE  8388608    // Bsz*Tlen*Cdim

typedef unsigned int u32;
typedef _Float16 f16;
typedef __attribute__((ext_vector_type(8))) _Float16 f16x8;
typedef __attribute__((ext_vector_type(4))) float floatx4;
#define MFMA_F16(a,b,c) __builtin_amdgcn_mfma_f32_16x16x32_f16((a),(b),(c),0,0,0)

union pun8 { uint4 u; f16x8 f; };

__device__ __forceinline__ u32 pack2(f16 a, f16 b) {
    return (u32)__builtin_bit_cast(unsigned short, a) |
           ((u32)__builtin_bit_cast(unsigned short, b) << 16);
}
__device__ __forceinline__ u32 splitpack(float v) {
    f16 h = (f16)v;
    f16 l = (f16)(v - (float)h);
    return pack2(h, l);
}
// 8 packed (h|l) u32 -> hi f16x8 + lo f16x8 (v_perm_b32)
__device__ __forceinline__ void unpack8(const u32* p, f16x8& h, f16x8& l) {
    uint4 q0 = *(const uint4*)p;
    uint4 q1 = *(const uint4*)(p + 4);
    pun8 ph, pl;
    ph.u.x = __builtin_amdgcn_perm(q0.y, q0.x, 0x05040100u);
    pl.u.x = __builtin_amdgcn_perm(q0.y, q0.x, 0x07060302u);
    ph.u.y = __builtin_amdgcn_perm(q0.w, q0.z, 0x05040100u);
    pl.u.y = __builtin_amdgcn_perm(q0.w, q0.z, 0x07060302u);
    ph.u.z = __builtin_amdgcn_perm(q1.y, q1.x, 0x05040100u);
    pl.u.z = __builtin_amdgcn_perm(q1.y, q1.x, 0x07060302u);
    ph.u.w = __builtin_amdgcn_perm(q1.w, q1.z, 0x05040100u);
    pl.u.w = __builtin_amdgcn_perm(q1.w, q1.z, 0x07060302u);
    h = ph.f; l = pl.f;
}
__device__ __forceinline__ float tanh_fast(float x) {
    return 1.0f - 2.0f / (__expf(2.0f * x) + 1.0f);
}

// ---------------------------------------------------------------------------
// Kernel A (fused prep): blocks 0..2047 = X -> f16; 2048..2239 = W transpose
// -> WT f16 [mat][n][k]; 2240 = gamma scan + decay tables + per-t-tile s_lo.
// ---------------------------------------------------------------------------
__global__ __launch_bounds__(256) void prep_kernel(
    const float* __restrict__ X,
    const float* __restrict__ WQ, const float* __restrict__ WK,
    const float* __restrict__ WV,
    f16* __restrict__ Xf, f16* __restrict__ WT,
    float* __restrict__ Lg, float* __restrict__ Wfin, int* __restrict__ sLo) {
    __shared__ char pshm[18432];
    int bid = blockIdx.x, tid = threadIdx.x;
    if (bid < 2048) {
        size_t i = ((size_t)bid * 256 + tid) * 16;
        float v[16];
#pragma unroll
        for (int j = 0; j < 4; ++j) {
            float4 a = *(const float4*)(X + i + j * 4);
            v[j*4+0]=a.x; v[j*4+1]=a.y; v[j*4+2]=a.z; v[j*4+3]=a.w;
        }
        uint4 o0, o1;
        o0.x = pack2((f16)v[0], (f16)v[1]);   o0.y = pack2((f16)v[2], (f16)v[3]);
        o0.z = pack2((f16)v[4], (f16)v[5]);   o0.w = pack2((f16)v[6], (f16)v[7]);
        o1.x = pack2((f16)v[8], (f16)v[9]);   o1.y = pack2((f16)v[10], (f16)v[11]);
        o1.z = pack2((f16)v[12], (f16)v[13]); o1.w = pack2((f16)v[14], (f16)v[15]);
        *(uint4*)(Xf + i) = o0;
        *(uint4*)(Xf + i + 8) = o1;
    } else if (bid < 2240) {
        f16* tile = (f16*)pshm;   // [64][72]
        int wb = bid - 2048;
        int mat = wb >> 6, rem = wb & 63;
        int k0 = (rem >> 3) * 64, n0 = (rem & 7) * 64;
        const float* W = (mat == 0) ? WQ : (mat == 1) ? WK : WV;
        int row = tid >> 2, q = tid & 3;
        const float* src = W + (size_t)(k0 + row) * Cdim + n0 + q * 16;
        float vv[16];
#pragma unroll
        for (int j = 0; j < 4; ++j) {
            float4 v = *(const float4*)(src + j * 4);
            vv[j*4+0]=v.x; vv[j*4+1]=v.y; vv[j*4+2]=v.z; vv[j*4+3]=v.w;
        }
#pragma unroll
        for (int j = 0; j < 16; ++j) tile[(q * 16 + j) * 72 + row] = (f16)vv[j];
        __syncthreads();
        f16x8 r0 = *(const f16x8*)(tile + row * 72 + q * 16);
        f16x8 r1 = *(const f16x8*)(tile + row * 72 + q * 16 + 8);
        f16* dst = WT + ((size_t)mat * Cdim + n0 + row) * Cdim + k0 + q * 16;
        *(f16x8*)dst = r0;
        *(f16x8*)(dst + 8) = r1;
    } else {
        float* Lsh = (float*)pshm;                 // 4097
        float* sums = (float*)(pshm + 16400);      // 256
        float lg[16];
        float local = 0.f;
        int base = tid * 16;
#pragma unroll
        for (int i = 0; i < 16; ++i) {
            int t = base + i;
            float g = 0.96f + 0.03f * ((float)t * (1.0f / 4095.0f));
            lg[i] = logf(g);
            local += lg[i];
        }
        sums[tid] = local;
        __syncthreads();
        for (int off = 1; off < 256; off <<= 1) {
            float v = sums[tid];
            if (tid >= off) v += sums[tid - off];
            __syncthreads();
            sums[tid] = v;
            __syncthreads();
        }
        float pre = (tid == 0) ? 0.f : sums[tid - 1];
#pragma unroll
        for (int i = 0; i < 16; ++i) {
            Lsh[base + i] = pre;
            pre += lg[i];
        }
        if (tid == 255) Lsh[4096] = pre;
        __syncthreads();
        for (int t = tid; t < 4097; t += 256) Lg[t] = Lsh[t];
        float LT = Lsh[4096];
        for (int s = tid; s < 4096; s += 256) Wfin[s] = __expf(LT - Lsh[s + 1]);
        if (tid < 64) {
            float ref = Lsh[tid * 64 + 1];
            int st_hi = tid >> 1;
            int lo = st_hi;
            for (int st = 0; st < st_hi; ++st)
                if (ref - Lsh[st * 128 + 128] > CUT) { lo = st; break; }
            sLo[tid] = lo;
        }
    }
}

// ---------------------------------------------------------------------------
// Kernel B: QKV projection, single-f16 MFMA GEMM, 128x128 tiles, 256 thr
// (4 waves, 64x64 microtile each), LDS-staged kc-chunks of 64 (swizzled).
// Outputs: Qf,Kf row-major f16; KT,VT transposed [b][c][t] f16.
// ---------------------------------------------------------------------------
__global__ __launch_bounds__(256, 2) void qkv_mfma(
    const f16* __restrict__ Xf, const f16* __restrict__ WT,
    const float* __restrict__ bQ, const float* __restrict__ bK,
    const float* __restrict__ bV,
    f16* __restrict__ Qf, f16* __restrict__ Kf,
    f16* __restrict__ KT, f16* __restrict__ VT) {
    __shared__ char smem[34816];
    u32* sX = (u32*)smem;              // [128][32] words, XOR-swizzled
    u32* sW = (u32*)(smem + 16384);
    f16* sB = (f16*)smem;              // epilogue bounce [128][136] (alias)

    int tid = threadIdx.x, lane = tid & 63, wid = tid >> 6;
    int l16 = lane & 15, quad = lane >> 4;
    int wm = wid & 1, wn = wid >> 1;
    int xb = blockIdx.x;               // 0..11 (mat*4 + n-tile)
    int mat = xb >> 2, n0 = (xb & 3) * 128;
    int m0 = blockIdx.y * 128;

    floatx4 acc[4][4];
#pragma unroll
    for (int i = 0; i < 4; ++i)
#pragma unroll
        for (int j = 0; j < 4; ++j) acc[i][j] = (floatx4)0.f;

    int srow = tid >> 1, shalf = tid & 1;
    int arow_a = wm * 64 + l16, arow_b = wn * 64 + l16;
    int swz_f = (l16 & 7) << 2;

    for (int kc = 0; kc < Cdim; kc += 64) {
        __syncthreads();
        {
            const f16* gx = Xf + (size_t)(m0 + srow) * Cdim + kc + shalf * 32;
            const f16* gw = WT + ((size_t)(mat * Cdim) + n0 + srow) * Cdim + kc + shalf * 32;
            int wswz = (srow & 7) << 2;
#pragma unroll
            for (int k = 0; k < 4; ++k) {
                uint4 xv = *(const uint4*)(gx + k * 8);
                uint4 wv = *(const uint4*)(gw + k * 8);
                int w = shalf * 16 + k * 4;
                *(uint4*)&sX[srow * 32 + (w ^ wswz)] = xv;
                *(uint4*)&sW[srow * 32 + (w ^ wswz)] = wv;
            }
        }
        __syncthreads();
#pragma unroll
        for (int ks = 0; ks < 2; ++ks) {
            int w0 = ks * 16 + quad * 4;
            f16x8 af[4], bf[4];
#pragma unroll
            for (int mt = 0; mt < 4; ++mt)
                af[mt] = ((pun8*)&sX[(arow_a + mt * 16) * 32 + (w0 ^ swz_f)])->f;
#pragma unroll
            for (int nt = 0; nt < 4; ++nt)
                bf[nt] = ((pun8*)&sW[(arow_b + nt * 16) * 32 + (w0 ^ swz_f)])->f;
#pragma unroll
            for (int mt = 0; mt < 4; ++mt)
#pragma unroll
                for (int nt = 0; nt < 4; ++nt)
                    acc[mt][nt] = MFMA_F16(af[mt], bf[nt], acc[mt][nt]);
        }
    }

    const float* bias = (mat == 0) ? bQ : (mat == 1) ? bK : bV;
    float bv[4];
#pragma unroll
    for (int nt = 0; nt < 4; ++nt) bv[nt] = bias[n0 + wn * 64 + nt * 16 + l16];
    float cv[4][4][4];
#pragma unroll
    for (int mt = 0; mt < 4; ++mt)
#pragma unroll
        for (int nt = 0; nt < 4; ++nt)
#pragma unroll
            for (int r = 0; r < 4; ++r) cv[mt][nt][r] = acc[mt][nt][r] + bv[nt];

    int b = m0 >> 12, tloc = m0 & 4095;

    if (mat == 2) {
        // V -> VT only
#pragma unroll
        for (int mt = 0; mt < 4; ++mt)
#pragma unroll
            for (int nt = 0; nt < 4; ++nt) {
                int d = n0 + wn * 64 + nt * 16 + l16;
                int t = tloc + wm * 64 + mt * 16 + quad * 4;
                uint2 w;
                w.x = pack2((f16)cv[mt][nt][0], (f16)cv[mt][nt][1]);
                w.y = pack2((f16)cv[mt][nt][2], (f16)cv[mt][nt][3]);
                *(uint2*)(VT + ((size_t)(b * Cdim + d)) * Tlen + t) = w;
            }
    } else {
        if (mat == 1) {
            // K -> KT direct
#pragma unroll
            for (int mt = 0; mt < 4; ++mt)
#pragma unroll
                for (int nt = 0; nt < 4; ++nt) {
                    int d = n0 + wn * 64 + nt * 16 + l16;
                    int t = tloc + wm * 64 + mt * 16 + quad * 4;
                    uint2 w;
                    w.x = pack2((f16)cv[mt][nt][0], (f16)cv[mt][nt][1]);
                    w.y = pack2((f16)cv[mt][nt][2], (f16)cv[mt][nt][3]);
                    *(uint2*)(KT + ((size_t)(b * Cdim + d)) * Tlen + t) = w;
                }
        }
        // row-major via LDS bounce
        __syncthreads();
#pragma unroll
        for (int mt = 0; mt < 4; ++mt)
#pragma unroll
            for (int nt = 0; nt < 4; ++nt)
#pragma unroll
                for (int r = 0; r < 4; ++r)
                    sB[(wm * 64 + mt * 16 + quad * 4 + r) * 136 +
                       wn * 64 + nt * 16 + l16] = (f16)cv[mt][nt][r];
        __syncthreads();
        {
            f16* Out = (mat == 0) ? Qf : Kf;
            int r2 = tid >> 1, h2 = tid & 1;
            f16* dst = Out + (size_t)(m0 + r2) * Cdim + n0 + h2 * 64;
#pragma unroll
            for (int j = 0; j < 8; ++j)
                *(uint4*)(dst + j * 8) = *(const uint4*)(sB + r2 * 136 + h2 * 64 + j * 8);
        }
    }
}

// ---------------------------------------------------------------------------
// Kernel C: attention. Grid exactly 256: block = (b, t-tile64), owns its
// whole t-tile -> no atomics, tanh fused. 512 thr (8 waves). Q-tile staged
// once in LDS (XOR-swizzled, reused across all s-items); K,V fragments
// direct from global (2x wave redundancy -> L2 hit). P transits LDS packed
// h|l u32 (round-4 proven swizzle). 2 barriers per item.
// ---------------------------------------------------------------------------
__global__ __launch_bounds__(512, 2) void attn_mfma(
    const f16* __restrict__ Qf, const f16* __restrict__ Kf,
    const f16* __restrict__ VT, const float* __restrict__ Lg,
    const int* __restrict__ sLo, float* __restrict__ out) {
    __shared__ char smem[99328];
    u32* sQ  = (u32*)smem;             // [64][256] words (64 KB)
    u32* sPc = (u32*)(smem + 65536);   // [64][132]  (33.8 KB)

    int tid = threadIdx.x, lane = tid & 63, wid = tid >> 6;
    int l16 = lane & 15, quad = lane >> 4;
    int mw = wid & 1;        // t-half (phases 1 & 2)
    int nw = wid >> 1;       // phase1 s-strip (32) / phase2 d-strip (128)

    int x = blockIdx.x & 7, j = blockIdx.x >> 3;
    int b = x >> 1;
    int tt = (j << 1) | (x & 1);       // parity-interleave for XCD balance
    int t0 = tt * 64;
    size_t bT = (size_t)b * Tlen;
    int lo = sLo[tt], hi = tt >> 1;

    // ---- stage Q tile (64 rows x 512 f16) into swizzled LDS
    {
        int r = tid >> 3, c8 = tid & 7;
        const f16* src = Qf + (bT + t0 + r) * Cdim + c8 * 64;
        int wswz = (r & 7) << 2;
#pragma unroll
        for (int k = 0; k < 8; ++k) {
            uint4 v = *(const uint4*)(src + k * 8);
            int w = c8 * 32 + k * 4;
            *(uint4*)&sQ[r * 256 + (w ^ wswz)] = v;
        }
    }

    float aT[2][4];
#pragma unroll
    for (int mt = 0; mt < 2; ++mt)
#pragma unroll
        for (int r = 0; r < 4; ++r)
            aT[mt][r] = Lg[t0 + mw * 32 + mt * 16 + quad * 4 + r + 1];

    floatx4 oacc[2][8];
#pragma unroll
    for (int i = 0; i < 2; ++i)
#pragma unroll
        for (int jj = 0; jj < 8; ++jj) oacc[i][jj] = (floatx4)0.f;

    int swz_f = (l16 & 7) << 2;
    int rowA0 = (mw * 32 + l16) * 256;
    int rowA1 = (mw * 32 + 16 + l16) * 256;

    __syncthreads();

    for (int st = lo; st <= hi; ++st) {
        int s0 = st * 128;
        float lsp[2];
#pragma unroll
        for (int sq = 0; sq < 2; ++sq)
            lsp[sq] = Lg[s0 + nw * 32 + sq * 16 + l16 + 1];

        floatx4 pacc[2][2];
#pragma unroll
        for (int i = 0; i < 2; ++i)
#pragma unroll
            for (int jj = 0; jj < 2; ++jj) pacc[i][jj] = (floatx4)0.f;

        // ---- phase 1: P = Q . K^T  (Q from LDS, K direct global)
        const f16* kb = Kf + (bT + s0 + nw * 32 + l16) * Cdim;
#pragma unroll 4
        for (int kc = 0; kc < 16; ++kc) {
            int ko = kc * 32 + quad * 8;
            int w0 = kc * 16 + quad * 4;
            f16x8 a0 = ((pun8*)&sQ[rowA0 + (w0 ^ swz_f)])->f;
            f16x8 a1 = ((pun8*)&sQ[rowA1 + (w0 ^ swz_f)])->f;
            f16x8 b0 = *(const f16x8*)(kb + ko);
            f16x8 b1 = *(const f16x8*)(kb + 16 * Cdim + ko);
            pacc[0][0] = MFMA_F16(a0, b0, pacc[0][0]);
            pacc[0][1] = MFMA_F16(a0, b1, pacc[0][1]);
            pacc[1][0] = MFMA_F16(a1, b0, pacc[1][0]);
            pacc[1][1] = MFMA_F16(a1, b1, pacc[1][1]);
        }

        // ---- weight + mask + split into LDS
        __syncthreads();   // prior phase2 done reading sPc
#pragma unroll
        for (int mt = 0; mt < 2; ++mt)
#pragma unroll
            for (int sq = 0; sq < 2; ++sq)
#pragma unroll
                for (int r = 0; r < 4; ++r) {
                    int tl = mw * 32 + mt * 16 + quad * 4 + r;
                    int sl = nw * 32 + sq * 16 + l16;
                    int t = t0 + tl, s = s0 + sl;
                    float p = pacc[mt][sq][r];
                    p = (s <= t) ? p * __expf(aT[mt][r] - lsp[sq]) : 0.f;
                    sPc[tl * 132 + (sl ^ ((tl & 7) << 4))] = splitpack(p);
                }
        __syncthreads();

        // ---- phase 2: O += (Ph+Pl) . V  (P from LDS, V direct global)
        const f16* vb = VT + ((size_t)(b * Cdim + nw * 128 + l16)) * Tlen + s0;
#pragma unroll
        for (int kf = 0; kf < 4; ++kf) {
            int sb = kf * 32 + quad * 8;
            f16x8 ph[2], pl[2];
#pragma unroll
            for (int mt = 0; mt < 2; ++mt) {
                int tl = mw * 32 + mt * 16 + l16;
                unpack8(&sPc[tl * 132 + (sb ^ ((tl & 7) << 4))], ph[mt], pl[mt]);
            }
#pragma unroll
            for (int nt = 0; nt < 8; ++nt) {
                f16x8 vf = *(const f16x8*)(vb + (size_t)nt * 16 * Tlen + sb);
#pragma unroll
                for (int mt = 0; mt < 2; ++mt) {
                    oacc[mt][nt] = MFMA_F16(ph[mt], vf, oacc[mt][nt]);
                    oacc[mt][nt] = MFMA_F16(pl[mt], vf, oacc[mt][nt]);
                }
            }
        }
    }

    // ---- epilogue: fused tanh + direct store
#pragma unroll
    for (int mt = 0; mt < 2; ++mt)
#pragma unroll
        for (int nt = 0; nt < 8; ++nt)
#pragma unroll
            for (int r = 0; r < 4; ++r) {
                int t = t0 + mw * 32 + mt * 16 + quad * 4 + r;
                int d = nw * 128 + nt * 16 + l16;
                out[(bT + t) * (size_t)Cdim + d] = tanh_fast(oacc[mt][nt][r]);
            }
}

// ---------------------------------------------------------------------------
// Kernel D: S_final = sum_s Wfin[s] * K[s]^T V[s] via f16 MFMA on KT/VT.
// ---------------------------------------------------------------------------
__global__ __launch_bounds__(256) void sfinal_mfma(
    const f16* __restrict__ KT, const f16* __restrict__ VT,
    const float* __restrict__ Lg, const float* __restrict__ Wfin,
    float* __restrict__ S) {
    __shared__ f16 sA[64 * 72];
    __shared__ f16 sB2[64 * 72];
    int tid = threadIdx.x, lane = tid & 63, wid = tid >> 6;
    int l16 = lane & 15, quad = lane >> 4;
    int wv_c = wid & 1, wv_d = wid >> 1;
    int c0 = blockIdx.x * 64, d0 = blockIdx.y * 64, b = blockIdx.z;
    float LT = Lg[Tlen];
    floatx4 acc[2][2];
#pragma unroll
    for (int i = 0; i < 2; ++i)
#pragma unroll
        for (int jj = 0; jj < 2; ++jj) acc[i][jj] = (floatx4)0.f;

    int s0start = Tlen - 64;
    for (int s0 = 0; s0 < Tlen; s0 += 64)
        if (LT - Lg[s0 + 64] > CUT) { s0start = s0; break; }

    int row = tid >> 2, q = tid & 3;
    for (int s0 = s0start; s0 < Tlen; s0 += 64) {
        __syncthreads();
        {
            const f16* g = KT + ((size_t)(b * Cdim + c0 + row)) * Tlen + s0 + q * 16;
            f16x8 u0 = *(const f16x8*)g;
            f16x8 u1 = *(const f16x8*)(g + 8);
            float wv[16];
#pragma unroll
            for (int jj = 0; jj < 4; ++jj) {
                float4 w4 = *(const float4*)(Wfin + s0 + q * 16 + jj * 4);
                wv[jj*4+0]=w4.x; wv[jj*4+1]=w4.y; wv[jj*4+2]=w4.z; wv[jj*4+3]=w4.w;
            }
            f16x8 o0, o1;
#pragma unroll
            for (int jj = 0; jj < 8; ++jj) o0[jj] = (f16)((float)u0[jj] * wv[jj]);
#pragma unroll
            for (int jj = 0; jj < 8; ++jj) o1[jj] = (f16)((float)u1[jj] * wv[8 + jj]);
            *(f16x8*)(sA + row * 72 + q * 16) = o0;
            *(f16x8*)(sA + row * 72 + q * 16 + 8) = o1;
            const f16* gv = VT + ((size_t)(b * Cdim + d0 + row)) * Tlen + s0 + q * 16;
            uint4 v0 = *(const uint4*)gv, v1 = *(const uint4*)(gv + 8);
            *(uint4*)(sB2 + row * 72 + q * 16) = v0;
            *(uint4*)(sB2 + row * 72 + q * 16 + 8) = v1;
        }
        __syncthreads();
#pragma unroll
        for (int ks = 0; ks < 2; ++ks) {
            int ko = ks * 32 + quad * 8;
            f16x8 a0 = *(const f16x8*)(sA + (wv_c * 32 + l16) * 72 + ko);
            f16x8 a1 = *(const f16x8*)(sA + (wv_c * 32 + 16 + l16) * 72 + ko);
            f16x8 b0 = *(const f16x8*)(sB2 + (wv_d * 32 + l16) * 72 + ko);
            f16x8 b1 = *(const f16x8*)(sB2 + (wv_d * 32 + 16 + l16) * 72 + ko);
            acc[0][0] = MFMA_F16(a0, b0, acc[0][0]);
            acc[0][1] = MFMA_F16(a0, b1, acc[0][1]);
            acc[1][0] = MFMA_F16(a1, b0, acc[1][0]);
            acc[1][1] = MFMA_F16(a1, b1, acc[1][1]);
        }
    }
#pragma unroll
    for (int ct = 0; ct < 2; ++ct)
#pragma unroll
        for (int dt = 0; dt < 2; ++dt)
#pragma unroll
            for (int r = 0; r < 4; ++r) {
                int c = c0 + wv_c * 32 + ct * 16 + quad * 4 + r;
                int d = d0 + wv_d * 32 + dt * 16 + l16;
                S[((size_t)(b * Cdim + c)) * Cdim + d] = acc[ct][dt][r];
            }
}

// ---------------------------------------------------------------------------
extern "C" void kernel_launch(void* const* d_in, const int* in_sizes, int n_in,
                              void* d_out, int out_size, void* d_ws, size_t ws_size,
                              hipStream_t stream) {
    (void)in_sizes; (void)n_in; (void)out_size; (void)ws_size;
    const float* X  = (const float*)d_in[0];
    const float* WQ = (const float*)d_in[2];
    const float* bQ = (const float*)d_in[3];
    const float* WK = (const float*)d_in[4];
    const float* bK = (const float*)d_in[5];
    const float* WV = (const float*)d_in[6];
    const float* bV = (const float*)d_in[7];

    float* out   = (float*)d_out;
    float* S_out = out + (size_t)NBE;

    char* ws = (char*)d_ws;
    f16*   Xf   = (f16*)(ws);                       // 2*NBE bytes each
    f16*   Qf   = (f16*)(ws + 2ull * NBE);
    f16*   Kf   = (f16*)(ws + 4ull * NBE);
    f16*   KT   = (f16*)(ws + 6ull * NBE);
    f16*   VT   = (f16*)(ws + 8ull * NBE);
    f16*   WT   = (f16*)(ws + 10ull * NBE);         // 1.5 MB
    char*  tail = ws + 10ull * NBE + (2u << 20);
    float* Lg   = (float*)(tail);                   // 4097
    float* Wfin = (float*)(tail + 16512);           // 4096
    int*   sLo  = (int*)(tail + 16512 + 16384);     // 64

    prep_kernel<<<2241, 256, 0, stream>>>(X, WQ, WK, WV, Xf, WT, Lg, Wfin, sLo);
    qkv_mfma<<<dim3(12, 128), 256, 0, stream>>>(Xf, WT, bQ, bK, bV, Qf, Kf, KT, VT);
    attn_mfma<<<256, 512, 0, stream>>>(Qf, Kf, VT, Lg, sLo, out);
    sfinal_mfma<<<dim3(8, 8, Bsz), 256, 0, stream>>>(KT, VT, Lg, Wfin, S_out);
}